// Round 2
// baseline (6651.315 us; speedup 1.0000x reference)
//
#include <hip/hip_runtime.h>
#include <stdint.h>

#define B_ 512
#define L_ 48
#define D_ 256

typedef __attribute__((ext_vector_type(8))) short bf16x8;
typedef __attribute__((ext_vector_type(4))) short bf16x4;
typedef __attribute__((ext_vector_type(4))) float f32x4;

__device__ __forceinline__ short f2bf(float f) {
    union { float f; unsigned u; } v; v.f = f;
    unsigned u = v.u;
    unsigned r = (u + 0x7FFFu + ((u >> 16) & 1u)) >> 16;
    return (short)r;
}
__device__ __forceinline__ float bf2f(short s) {
    union { unsigned u; float f; } v; v.u = ((unsigned)(unsigned short)s) << 16;
    return v.f;
}

// ---------------- weight prep: fp32 -> bf16, concat [w_hh;w_h] ----------------
__global__ __launch_bounds__(256) void k_prep(const float* __restrict__ w_hh,
                                              const float* __restrict__ w_h,
                                              const float* __restrict__ w_ih,
                                              short* __restrict__ W1,
                                              short* __restrict__ W2) {
    int t = blockIdx.x * 256 + threadIdx.x;
    const int N1 = 768 * 256;
    const int N1b = 816 * 256;
    if (t < N1) {
        W1[t] = f2bf(w_hh[t]);
    } else if (t < N1b) {
        W1[t] = f2bf(w_h[t - N1]);
    } else {
        int u = t - N1b;
        if (u < 768 * 256) W2[u] = f2bf(w_ih[u]);
    }
}

// ---------------- embedding GEMM: x = relu(x1@we1^T+b1) + relu(x2@we2^T+b2) ----
__device__ __forceinline__ void gemm_pass(const float* __restrict__ X,
                                          const float* __restrict__ W,
                                          short (*sA)[40], short (*sB)[40],
                                          int m0, int n0, int srow, int sseg,
                                          int mf, int nf, int row16, int kg,
                                          f32x4 (&acc)[2][4]) {
    for (int k0 = 0; k0 < 512; k0 += 32) {
        __syncthreads();
        {
            const float* src = X + (size_t)(m0 + srow) * 512 + k0 + sseg * 8;
            float4 p0 = *(const float4*)(src);
            float4 p1 = *(const float4*)(src + 4);
            bf16x8 v;
            v[0] = f2bf(p0.x); v[1] = f2bf(p0.y); v[2] = f2bf(p0.z); v[3] = f2bf(p0.w);
            v[4] = f2bf(p1.x); v[5] = f2bf(p1.y); v[6] = f2bf(p1.z); v[7] = f2bf(p1.w);
            *(bf16x8*)&sA[srow][sseg * 8] = v;
        }
        {
            const float* src = W + (size_t)(n0 + srow) * 512 + k0 + sseg * 8;
            float4 p0 = *(const float4*)(src);
            float4 p1 = *(const float4*)(src + 4);
            bf16x8 v;
            v[0] = f2bf(p0.x); v[1] = f2bf(p0.y); v[2] = f2bf(p0.z); v[3] = f2bf(p0.w);
            v[4] = f2bf(p1.x); v[5] = f2bf(p1.y); v[6] = f2bf(p1.z); v[7] = f2bf(p1.w);
            *(bf16x8*)&sB[srow][sseg * 8] = v;
        }
        __syncthreads();
        bf16x8 a0 = *(bf16x8*)&sA[(mf + 0) * 16 + row16][kg * 8];
        bf16x8 a1 = *(bf16x8*)&sA[(mf + 1) * 16 + row16][kg * 8];
        #pragma unroll
        for (int j = 0; j < 4; ++j) {
            bf16x8 bv = *(bf16x8*)&sB[(nf + j) * 16 + row16][kg * 8];
            acc[0][j] = __builtin_amdgcn_mfma_f32_16x16x32_bf16(a0, bv, acc[0][j], 0, 0, 0);
            acc[1][j] = __builtin_amdgcn_mfma_f32_16x16x32_bf16(a1, bv, acc[1][j], 0, 0, 0);
        }
    }
}

__global__ __launch_bounds__(512) void k_embed(const float* __restrict__ x1,
                                               const float* __restrict__ x2,
                                               const float* __restrict__ w_e1,
                                               const float* __restrict__ b_e1,
                                               const float* __restrict__ w_e2,
                                               const float* __restrict__ b_e2,
                                               short* __restrict__ xb) {
    __shared__ short sA[128][40];
    __shared__ short sB[128][40];
    int bid = blockIdx.x;
    int mt = bid >> 1, nt = bid & 1;
    int m0 = mt * 128, n0 = nt * 128;
    int tid = threadIdx.x;
    int lane = tid & 63, w = tid >> 6;
    int mf = (w & 3) * 2;
    int nf = (w >> 2) * 4;
    int row16 = lane & 15, kg = lane >> 4;
    int srow = tid >> 2, sseg = tid & 3;

    f32x4 acc[2][4], keep[2][4];
    #pragma unroll
    for (int a = 0; a < 2; ++a)
        #pragma unroll
        for (int j = 0; j < 4; ++j) { acc[a][j] = {0.f, 0.f, 0.f, 0.f}; }

    gemm_pass(x1, w_e1, sA, sB, m0, n0, srow, sseg, mf, nf, row16, kg, acc);
    #pragma unroll
    for (int a = 0; a < 2; ++a)
        #pragma unroll
        for (int j = 0; j < 4; ++j) { keep[a][j] = acc[a][j]; acc[a][j] = {0.f, 0.f, 0.f, 0.f}; }
    gemm_pass(x2, w_e2, sA, sB, m0, n0, srow, sseg, mf, nf, row16, kg, acc);

    #pragma unroll
    for (int a = 0; a < 2; ++a) {
        int mbase = m0 + (mf + a) * 16 + kg * 4;
        #pragma unroll
        for (int j = 0; j < 4; ++j) {
            int n = n0 + (nf + j) * 16 + row16;
            float be1 = b_e1[n], be2 = b_e2[n];
            #pragma unroll
            for (int e = 0; e < 4; ++e) {
                float v1 = fmaxf(keep[a][j][e] + be1, 0.f);
                float v2 = fmaxf(acc[a][j][e] + be2, 0.f);
                xb[(size_t)(mbase + e) * 256 + n] = f2bf(v1 + v2);
            }
        }
    }
}

// ------------- aux: exact fp32 channel-0 of x2e (for cond), and xw = x . w_x ----
__global__ __launch_bounds__(256) void k_aux(const float* __restrict__ x2,
                                             const float* __restrict__ w_e2,
                                             const float* __restrict__ b_e2,
                                             const short* __restrict__ xb,
                                             const float* __restrict__ w_x,
                                             float* __restrict__ c0,
                                             float* __restrict__ xw) {
    int w = threadIdx.x >> 6, lane = threadIdx.x & 63;
    int m = blockIdx.x * 4 + w;
    const float* xr = x2 + (size_t)m * 512 + lane * 8;
    const float* wr = w_e2 + lane * 8;
    float s = 0.f;
    #pragma unroll
    for (int q = 0; q < 8; ++q) s += xr[q] * wr[q];
    #pragma unroll
    for (int o = 32; o; o >>= 1) s += __shfl_xor(s, o);
    float pre = s + b_e2[0];

    float t = 0.f;
    if (lane < 32) {
        const short* xbr = xb + (size_t)m * 256 + lane * 8;
        #pragma unroll
        for (int q = 0; q < 8; ++q) t += bf2f(xbr[q]) * w_x[lane * 8 + q];
    }
    #pragma unroll
    for (int o = 32; o; o >>= 1) t += __shfl_xor(t, o);
    if (lane == 0) { c0[m] = fmaxf(pre, 0.f); xw[m] = t; }
}

// ------------- aux2: cond bitmasks per batch + se = s@w_s^T + b_s --------------
__global__ __launch_bounds__(256) void k_aux2(const float* __restrict__ c0,
                                              const float* __restrict__ s_in,
                                              const float* __restrict__ w_s,
                                              const float* __restrict__ b_s,
                                              unsigned long long* __restrict__ condbits,
                                              float* __restrict__ se) {
    __shared__ float sS[64];
    int b = blockIdx.x;
    int t = threadIdx.x;
    if (t < 64) sS[t] = s_in[b * 64 + t];
    __syncthreads();
    float acc = b_s[t];
    const float* wr = w_s + t * 64;
    #pragma unroll 8
    for (int kk = 0; kk < 64; ++kk) acc += sS[kk] * wr[kk];
    se[(size_t)b * 256 + t] = acc;
    if (t == 0) {
        unsigned long long bits = 0;
        bool run = true;
        const float* cr = c0 + (size_t)b * 48;
        for (int i = 0; i < 48; ++i) {
            if (run) bits |= (1ull << i);
            run = run && (cr[i] == 0.0f);
        }
        condbits[b] = bits;
    }
}

// ---------------- group barrier: 8 slice-blocks of one batch group -------------
__device__ __forceinline__ void group_barrier(int* cnt, int target, int tid) {
    __threadfence();
    __syncthreads();
    if (tid == 0) {
        __hip_atomic_fetch_add(cnt, 1, __ATOMIC_RELEASE, __HIP_MEMORY_SCOPE_AGENT);
        while (__hip_atomic_load(cnt, __ATOMIC_ACQUIRE, __HIP_MEMORY_SCOPE_AGENT) < target) {
            __builtin_amdgcn_s_sleep(1);
        }
    }
    __syncthreads();
    __threadfence();
}

// ---------------- persistent sliced scan: 256 blocks = 32 groups x 8 slices ----
__global__ __launch_bounds__(512) void k_scan(const short* __restrict__ W1,
                                              const short* __restrict__ W2,
                                              const float* __restrict__ b_hh,
                                              const float* __restrict__ b_h,
                                              const float* __restrict__ b_ih,
                                              const short* __restrict__ xb,
                                              const float* __restrict__ xw,
                                              const unsigned long long* __restrict__ condbits,
                                              const float* __restrict__ se,
                                              const float* __restrict__ w_out,
                                              const float* __restrict__ b_out,
                                              short* __restrict__ ctxX,
                                              short* __restrict__ hX,
                                              float* __restrict__ partY,
                                              int* __restrict__ flags,
                                              float* __restrict__ out) {
    __shared__ short lA[16][264];     // shared bf16 operand: h, then ctx
    __shared__ float Ghh[16][97];     // h-side gates (r|z|hn) for this slice
    __shared__ float Gii[16][97];     // input-side gates (r|z|in)
    __shared__ float lW[16][49];      // attention scores h@w_h^T + b_h
    __shared__ float lT[16][49];      // softmax a
    __shared__ float lXW[16][48];
    __shared__ float lHs[16][33];     // fp32 GRU state, this slice's 32 dims
    __shared__ unsigned long long lC[16];

    const int tid = threadIdx.x;
    const int w = tid >> 6, lane = tid & 63;
    const int row16 = lane & 15, kg = lane >> 4;
    const int blk = blockIdx.x;
    const int g = blk & 31, k = blk >> 5;   // same-group slices share XCD (blk%8==g%8)
    const int b0 = g * 16, d0 = k * 32;
    int* cnt = flags + g * 32;
    int bar = 0;

    // ---- persistent weight fragments (held in VGPRs all 48 steps) ----
    int rA = (w < 6) ? ((w >> 1) * 256 + d0 + (w & 1) * 16 + row16)
                     : (768 + (w - 6) * 16 + row16);
    float biasA = (w < 6) ? b_hh[rA] : b_h[rA - 768];
    const bool isA2 = (w == 0);
    const bool isC  = (w >= 1 && w <= 6);
    const int Tc = w - 1;
    int rX = isA2 ? (768 + 32 + row16)
                  : ((Tc >> 1) * 256 + d0 + (Tc & 1) * 16 + row16);
    float biasX = isA2 ? b_h[32 + row16] : (isC ? b_ih[rX] : 0.f);

    bf16x8 regA[8], regX[8];
    {
        const short* pa = W1 + (size_t)rA * 256 + kg * 8;
        #pragma unroll
        for (int s = 0; s < 8; ++s) regA[s] = *(const bf16x8*)(pa + s * 32);
        if (isA2 || isC) {
            const short* px = (isA2 ? W1 : W2) + (size_t)rX * 256 + kg * 8;
            #pragma unroll
            for (int s = 0; s < 8; ++s) regX[s] = *(const bf16x8*)(px + s * 32);
        }
    }

    for (int t = tid; t < 16 * 48; t += 512) {
        int m = t / 48, j = t - m * 48;
        lXW[m][j] = xw[(size_t)(b0 + m) * 48 + j];
    }
    if (tid < 16) lC[tid] = condbits[b0 + tid];
    for (int t = tid; t < 528; t += 512) {
        bf16x8 z = {};
        ((bf16x8*)lA)[t] = z;
        ((float*)lHs)[t] = 0.f;
    }
    __syncthreads();

    const size_t xbase = (size_t)b0 * 48 * 256;
    const int mi = tid >> 5, dd = tid & 31;
    const int dglob = d0 + dd;

    for (int i = 0; i < 48; ++i) {
        // ---- Phase A: gh/hW = h @ W1_slice^T (weights from registers) ----
        bf16x8 av[8];
        #pragma unroll
        for (int s = 0; s < 8; ++s) av[s] = *(const bf16x8*)&lA[row16][kg * 8 + s * 32];
        {
            f32x4 acc = {0.f, 0.f, 0.f, 0.f};
            #pragma unroll
            for (int s = 0; s < 8; ++s)
                acc = __builtin_amdgcn_mfma_f32_16x16x32_bf16(av[s], regA[s], acc, 0, 0, 0);
            if (w < 6) {
                #pragma unroll
                for (int e = 0; e < 4; ++e) Ghh[kg * 4 + e][w * 16 + row16] = acc[e] + biasA;
            } else {
                #pragma unroll
                for (int e = 0; e < 4; ++e) lW[kg * 4 + e][(w - 6) * 16 + row16] = acc[e] + biasA;
            }
            if (isA2) {
                f32x4 a2 = {0.f, 0.f, 0.f, 0.f};
                #pragma unroll
                for (int s = 0; s < 8; ++s)
                    a2 = __builtin_amdgcn_mfma_f32_16x16x32_bf16(av[s], regX[s], a2, 0, 0, 0);
                #pragma unroll
                for (int e = 0; e < 4; ++e) lW[kg * 4 + e][32 + row16] = a2[e] + biasX;
            }
        }
        __syncthreads();

        // ---- B1: softmax over all 48 positions (wave w -> batches 2w, 2w+1) ----
        #pragma unroll
        for (int rep = 0; rep < 2; ++rep) {
            int m = w * 2 + rep;
            float val = -3.0e38f;
            if (lane < 48) {
                val = lW[m][lane];
                bool cb = (lC[m] >> i) & 1ull;
                if (lane == i) val += lXW[m][i];
                else if (cb && lane < i) val += lXW[m][lane];
            }
            float mx = val;
            #pragma unroll
            for (int o = 32; o; o >>= 1) mx = fmaxf(mx, __shfl_xor(mx, o));
            float ex = (lane < 48) ? __expf(val - mx) : 0.f;
            float sm = ex;
            #pragma unroll
            for (int o = 32; o; o >>= 1) sm += __shfl_xor(sm, o);
            if (lane < 48) lT[m][lane] = ex / sm;
        }
        __syncthreads();

        // ---- B2: ctx slice (32 dims) in fp32, publish bf16 ----
        {
            const short* xr = xb + xbase + (size_t)mi * 12288 + dglob;
            float acc = 0.f;
            #pragma unroll 4
            for (int j = 0; j <= i; ++j) acc += lT[mi][j] * bf2f(xr[j * 256]);
            ctxX[(size_t)(b0 + mi) * 256 + dglob] = f2bf(acc);
        }
        group_barrier(cnt, 8 * (++bar), tid);
        {
            int m = tid >> 5, c8 = (tid & 31) * 8;
            bf16x8 v = *(const bf16x8*)(ctxX + (size_t)(b0 + m) * 256 + c8);
            *(bf16x8*)&lA[m][c8] = v;
        }
        __syncthreads();

        // ---- Phase C: gi = ctx @ W2_slice^T (weights from registers) ----
        if (isC) {
            bf16x8 cv[8];
            #pragma unroll
            for (int s = 0; s < 8; ++s) cv[s] = *(const bf16x8*)&lA[row16][kg * 8 + s * 32];
            f32x4 acc = {0.f, 0.f, 0.f, 0.f};
            #pragma unroll
            for (int s = 0; s < 8; ++s)
                acc = __builtin_amdgcn_mfma_f32_16x16x32_bf16(cv[s], regX[s], acc, 0, 0, 0);
            #pragma unroll
            for (int e = 0; e < 4; ++e) Gii[kg * 4 + e][Tc * 16 + row16] = acc[e] + biasX;
        }
        __syncthreads();

        // ---- Phase D: GRU update for this slice's 32 dims (fp32 state) ----
        {
            float gr = Ghh[mi][dd] + Gii[mi][dd];
            float gz = Ghh[mi][32 + dd] + Gii[mi][32 + dd];
            float r = 1.f / (1.f + __expf(-gr));
            float z = 1.f / (1.f + __expf(-gz));
            float nn = tanhf(Gii[mi][64 + dd] + r * Ghh[mi][64 + dd]);
            float hv = (1.f - z) * nn + z * lHs[mi][dd];
            lHs[mi][dd] = hv;
            hX[(size_t)(b0 + mi) * 256 + dglob] = f2bf(hv);
        }
        group_barrier(cnt, 8 * (++bar), tid);
        {
            int m = tid >> 5, c8 = (tid & 31) * 8;
            bf16x8 v = *(const bf16x8*)(hX + (size_t)(b0 + m) * 256 + c8);
            *(bf16x8*)&lA[m][c8] = v;
        }
        __syncthreads();
    }

    // ---- epilogue: partial dot over this slice's dims, then slice 0 combines ----
    {
        float v = (lHs[mi][dd] + se[(size_t)(b0 + mi) * 256 + dglob]) * w_out[dglob];
        #pragma unroll
        for (int o = 16; o; o >>= 1) v += __shfl_xor(v, o);
        if (dd == 0) partY[k * 512 + b0 + mi] = v;
    }
    group_barrier(cnt, 8 * (++bar), tid);
    if (k == 0 && tid < 16) {
        float sum = 0.f;
        #pragma unroll
        for (int q = 0; q < 8; ++q) sum += partY[q * 512 + b0 + tid];
        out[b0 + tid] = 1.f / (1.f + __expf(-(sum + b_out[0])));
    }
}

extern "C" void kernel_launch(void* const* d_in, const int* in_sizes, int n_in,
                              void* d_out, int out_size, void* d_ws, size_t ws_size,
                              hipStream_t stream) {
    const float* x1   = (const float*)d_in[0];
    const float* x2   = (const float*)d_in[1];
    const float* s    = (const float*)d_in[2];
    const float* w_e1 = (const float*)d_in[3];
    const float* b_e1 = (const float*)d_in[4];
    const float* w_e2 = (const float*)d_in[5];
    const float* b_e2 = (const float*)d_in[6];
    const float* w_s  = (const float*)d_in[7];
    const float* b_s  = (const float*)d_in[8];
    const float* w_x  = (const float*)d_in[9];
    const float* w_h  = (const float*)d_in[10];
    const float* b_h  = (const float*)d_in[11];
    const float* w_ih = (const float*)d_in[12];
    const float* w_hh = (const float*)d_in[13];
    const float* b_ih = (const float*)d_in[14];
    const float* b_hh = (const float*)d_in[15];
    const float* w_out = (const float*)d_in[16];
    const float* b_out = (const float*)d_in[17];
    float* out = (float*)d_out;

    char* ws = (char*)d_ws;
    size_t off = 0;
    auto alloc = [&](size_t bytes) -> void* {
        void* p = ws + off;
        off = (off + bytes + 255) & ~(size_t)255;
        return p;
    };
    short* xb = (short*)alloc((size_t)B_ * L_ * D_ * 2);
    short* W1 = (short*)alloc(816 * 256 * 2);
    short* W2 = (short*)alloc(768 * 256 * 2);
    float* c0 = (float*)alloc((size_t)B_ * L_ * 4);
    float* xw = (float*)alloc((size_t)B_ * L_ * 4);
    unsigned long long* cb = (unsigned long long*)alloc(B_ * 8);
    float* se = (float*)alloc((size_t)B_ * D_ * 4);
    short* ctxX = (short*)alloc((size_t)B_ * D_ * 2);
    short* hX   = (short*)alloc((size_t)B_ * D_ * 2);
    float* partY = (float*)alloc(8 * 512 * 4);
    int* flags = (int*)alloc(32 * 32 * 4);

    hipMemsetAsync(flags, 0, 32 * 32 * 4, stream);
    hipLaunchKernelGGL(k_prep, dim3((816 * 256 + 768 * 256) / 256), dim3(256), 0, stream,
                       w_hh, w_h, w_ih, W1, W2);
    hipLaunchKernelGGL(k_embed, dim3(384), dim3(512), 0, stream,
                       x1, x2, w_e1, b_e1, w_e2, b_e2, xb);
    hipLaunchKernelGGL(k_aux, dim3(6144), dim3(256), 0, stream,
                       x2, w_e2, b_e2, xb, w_x, c0, xw);
    hipLaunchKernelGGL(k_aux2, dim3(512), dim3(256), 0, stream,
                       c0, s, w_s, b_s, cb, se);
    hipLaunchKernelGGL(k_scan, dim3(256), dim3(512), 0, stream,
                       W1, W2, b_hh, b_h, b_ih, xb, xw, cb, se, w_out, b_out,
                       ctxX, hX, partY, flags, out);
}

// Round 3
// 1111.440 us; speedup vs baseline: 5.9844x; 5.9844x over previous
//
#include <hip/hip_runtime.h>
#include <stdint.h>

#define B_ 512
#define L_ 48
#define D_ 256

typedef __attribute__((ext_vector_type(8))) short bf16x8;
typedef __attribute__((ext_vector_type(4))) float f32x4;

__device__ __forceinline__ short f2bf(float f) {
    union { float f; unsigned u; } v; v.f = f;
    unsigned u = v.u;
    unsigned r = (u + 0x7FFFu + ((u >> 16) & 1u)) >> 16;
    return (short)r;
}
__device__ __forceinline__ float bf2f(short s) {
    union { unsigned u; float f; } v; v.u = ((unsigned)(unsigned short)s) << 16;
    return v.f;
}

// ---------------- weight prep: fp32 -> bf16, concat [w_hh;w_h] ----------------
__global__ __launch_bounds__(256) void k_prep(const float* __restrict__ w_hh,
                                              const float* __restrict__ w_h,
                                              const float* __restrict__ w_ih,
                                              short* __restrict__ W1,
                                              short* __restrict__ W2) {
    int t = blockIdx.x * 256 + threadIdx.x;
    const int N1 = 768 * 256;
    const int N1b = 816 * 256;
    if (t < N1) {
        W1[t] = f2bf(w_hh[t]);
    } else if (t < N1b) {
        W1[t] = f2bf(w_h[t - N1]);
    } else {
        int u = t - N1b;
        if (u < 768 * 256) W2[u] = f2bf(w_ih[u]);
    }
}

// ---------------- embedding GEMM: x = relu(x1@we1^T+b1) + relu(x2@we2^T+b2) ----
__device__ __forceinline__ void gemm_pass(const float* __restrict__ X,
                                          const float* __restrict__ W,
                                          short (*sA)[40], short (*sB)[40],
                                          int m0, int n0, int srow, int sseg,
                                          int mf, int nf, int row16, int kg,
                                          f32x4 (&acc)[2][4]) {
    for (int k0 = 0; k0 < 512; k0 += 32) {
        __syncthreads();
        {
            const float* src = X + (size_t)(m0 + srow) * 512 + k0 + sseg * 8;
            float4 p0 = *(const float4*)(src);
            float4 p1 = *(const float4*)(src + 4);
            bf16x8 v;
            v[0] = f2bf(p0.x); v[1] = f2bf(p0.y); v[2] = f2bf(p0.z); v[3] = f2bf(p0.w);
            v[4] = f2bf(p1.x); v[5] = f2bf(p1.y); v[6] = f2bf(p1.z); v[7] = f2bf(p1.w);
            *(bf16x8*)&sA[srow][sseg * 8] = v;
        }
        {
            const float* src = W + (size_t)(n0 + srow) * 512 + k0 + sseg * 8;
            float4 p0 = *(const float4*)(src);
            float4 p1 = *(const float4*)(src + 4);
            bf16x8 v;
            v[0] = f2bf(p0.x); v[1] = f2bf(p0.y); v[2] = f2bf(p0.z); v[3] = f2bf(p0.w);
            v[4] = f2bf(p1.x); v[5] = f2bf(p1.y); v[6] = f2bf(p1.z); v[7] = f2bf(p1.w);
            *(bf16x8*)&sB[srow][sseg * 8] = v;
        }
        __syncthreads();
        bf16x8 a0 = *(bf16x8*)&sA[(mf + 0) * 16 + row16][kg * 8];
        bf16x8 a1 = *(bf16x8*)&sA[(mf + 1) * 16 + row16][kg * 8];
        #pragma unroll
        for (int j = 0; j < 4; ++j) {
            bf16x8 bv = *(bf16x8*)&sB[(nf + j) * 16 + row16][kg * 8];
            acc[0][j] = __builtin_amdgcn_mfma_f32_16x16x32_bf16(a0, bv, acc[0][j], 0, 0, 0);
            acc[1][j] = __builtin_amdgcn_mfma_f32_16x16x32_bf16(a1, bv, acc[1][j], 0, 0, 0);
        }
    }
}

__global__ __launch_bounds__(512) void k_embed(const float* __restrict__ x1,
                                               const float* __restrict__ x2,
                                               const float* __restrict__ w_e1,
                                               const float* __restrict__ b_e1,
                                               const float* __restrict__ w_e2,
                                               const float* __restrict__ b_e2,
                                               short* __restrict__ xb) {
    __shared__ short sA[128][40];
    __shared__ short sB[128][40];
    int bid = blockIdx.x;
    int mt = bid >> 1, nt = bid & 1;
    int m0 = mt * 128, n0 = nt * 128;
    int tid = threadIdx.x;
    int lane = tid & 63, w = tid >> 6;
    int mf = (w & 3) * 2;
    int nf = (w >> 2) * 4;
    int row16 = lane & 15, kg = lane >> 4;
    int srow = tid >> 2, sseg = tid & 3;

    f32x4 acc[2][4], keep[2][4];
    #pragma unroll
    for (int a = 0; a < 2; ++a)
        #pragma unroll
        for (int j = 0; j < 4; ++j) { acc[a][j] = {0.f, 0.f, 0.f, 0.f}; }

    gemm_pass(x1, w_e1, sA, sB, m0, n0, srow, sseg, mf, nf, row16, kg, acc);
    #pragma unroll
    for (int a = 0; a < 2; ++a)
        #pragma unroll
        for (int j = 0; j < 4; ++j) { keep[a][j] = acc[a][j]; acc[a][j] = {0.f, 0.f, 0.f, 0.f}; }
    gemm_pass(x2, w_e2, sA, sB, m0, n0, srow, sseg, mf, nf, row16, kg, acc);

    #pragma unroll
    for (int a = 0; a < 2; ++a) {
        int mbase = m0 + (mf + a) * 16 + kg * 4;
        #pragma unroll
        for (int j = 0; j < 4; ++j) {
            int n = n0 + (nf + j) * 16 + row16;
            float be1 = b_e1[n], be2 = b_e2[n];
            #pragma unroll
            for (int e = 0; e < 4; ++e) {
                float v1 = fmaxf(keep[a][j][e] + be1, 0.f);
                float v2 = fmaxf(acc[a][j][e] + be2, 0.f);
                xb[(size_t)(mbase + e) * 256 + n] = f2bf(v1 + v2);
            }
        }
    }
}

// ------------- aux: exact fp32 channel-0 of x2e (for cond), and xw = x . w_x ----
__global__ __launch_bounds__(256) void k_aux(const float* __restrict__ x2,
                                             const float* __restrict__ w_e2,
                                             const float* __restrict__ b_e2,
                                             const short* __restrict__ xb,
                                             const float* __restrict__ w_x,
                                             float* __restrict__ c0,
                                             float* __restrict__ xw) {
    int w = threadIdx.x >> 6, lane = threadIdx.x & 63;
    int m = blockIdx.x * 4 + w;
    const float* xr = x2 + (size_t)m * 512 + lane * 8;
    const float* wr = w_e2 + lane * 8;
    float s = 0.f;
    #pragma unroll
    for (int q = 0; q < 8; ++q) s += xr[q] * wr[q];
    #pragma unroll
    for (int o = 32; o; o >>= 1) s += __shfl_xor(s, o);
    float pre = s + b_e2[0];

    float t = 0.f;
    if (lane < 32) {
        const short* xbr = xb + (size_t)m * 256 + lane * 8;
        #pragma unroll
        for (int q = 0; q < 8; ++q) t += bf2f(xbr[q]) * w_x[lane * 8 + q];
    }
    #pragma unroll
    for (int o = 32; o; o >>= 1) t += __shfl_xor(t, o);
    if (lane == 0) { c0[m] = fmaxf(pre, 0.f); xw[m] = t; }
}

// ------------- aux2: cond bitmasks per batch + se = s@w_s^T + b_s --------------
__global__ __launch_bounds__(256) void k_aux2(const float* __restrict__ c0,
                                              const float* __restrict__ s_in,
                                              const float* __restrict__ w_s,
                                              const float* __restrict__ b_s,
                                              unsigned long long* __restrict__ condbits,
                                              float* __restrict__ se) {
    __shared__ float sS[64];
    int b = blockIdx.x;
    int t = threadIdx.x;
    if (t < 64) sS[t] = s_in[b * 64 + t];
    __syncthreads();
    float acc = b_s[t];
    const float* wr = w_s + t * 64;
    #pragma unroll 8
    for (int kk = 0; kk < 64; ++kk) acc += sS[kk] * wr[kk];
    se[(size_t)b * 256 + t] = acc;
    if (t == 0) {
        unsigned long long bits = 0;
        bool run = true;
        const float* cr = c0 + (size_t)b * 48;
        for (int i = 0; i < 48; ++i) {
            if (run) bits |= (1ull << i);
            run = run && (cr[i] == 0.0f);
        }
        condbits[b] = bits;
    }
}

// ---------------- helpers for the scan's register-double-buffered GEMM ---------
__device__ __forceinline__ void load8(bf16x8 (&dst)[8], const short* p) {
    #pragma unroll
    for (int s = 0; s < 8; ++s) dst[s] = *(const bf16x8*)(p + s * 32);
}
__device__ __forceinline__ void mfma8(const bf16x8 (&a)[8], const bf16x8 (&b)[8], f32x4& acc) {
    #pragma unroll
    for (int s = 0; s < 8; ++s) acc = __builtin_amdgcn_mfma_f32_16x16x32_bf16(a[s], b[s], acc, 0, 0, 0);
}

// ---------------- persistent scan: 32 blocks x 16 batches, 48 steps ------------
// Weights streamed from L2 with fully-unrolled, register double-buffered tiles.
__global__ __launch_bounds__(512, 2) void k_scan(const short* __restrict__ W1,
                                                 const short* __restrict__ W2,
                                                 const float* __restrict__ b_hh,
                                                 const float* __restrict__ b_h,
                                                 const float* __restrict__ b_ih,
                                                 const short* __restrict__ xb,
                                                 const float* __restrict__ xw,
                                                 const unsigned long long* __restrict__ condbits,
                                                 const float* __restrict__ se,
                                                 const float* __restrict__ w_out,
                                                 const float* __restrict__ b_out,
                                                 float* __restrict__ out) {
    __shared__ float lH[16][256];
    __shared__ short lA[16][264];   // bf16 operand (h, then ctx)
    __shared__ float lG[16][820];   // r|z|hn gates (0..767) | attn scores (768..815)
    __shared__ float lN[16][260];   // i_n
    __shared__ float lT[16][48];    // softmax a
    __shared__ float lXW[16][48];
    __shared__ unsigned long long lC[16];

    const int tid = threadIdx.x;
    const int w = tid >> 6, lane = tid & 63;
    const int row16 = lane & 15, kg = lane >> 4;
    const int b0 = blockIdx.x * 16;

    // hoisted per-lane biases: one float per owned tile (n = t*16+row16)
    float biasA[7];
    #pragma unroll
    for (int u = 0; u < 7; ++u) {
        int t = u * 8 + w, n = t * 16 + row16;
        biasA[u] = (t < 48) ? b_hh[n] : ((t < 51) ? b_h[n - 768] : 0.f);
    }
    float biasC[6];
    #pragma unroll
    for (int u = 0; u < 6; ++u) { int n = (u * 8 + w) * 16 + row16; biasC[u] = b_ih[n]; }

    for (int t = tid; t < 16 * 48; t += 512) {
        int m = t / 48, j = t - m * 48;
        lXW[m][j] = xw[(size_t)(b0 + m) * 48 + j];
    }
    if (tid < 16) lC[tid] = condbits[b0 + tid];
    for (int t = tid; t < 16 * 256; t += 512) {
        int m = t >> 8, d = t & 255;
        lH[m][d] = 0.f;
        lA[m][d] = 0;
    }
    __syncthreads();

    const size_t xbase = (size_t)b0 * 48 * 256;
    const int mi = tid >> 5, dc8 = (tid & 31) * 8;
    const short* xr = xb + xbase + (size_t)mi * 12288 + dc8;

    // per-lane weight base pointers (tile u of a phase = +u*32768 shorts)
    const short* W1p = W1 + (size_t)(w * 16 + row16) * 256 + kg * 8;
    const short* W2p = W2 + (size_t)(w * 16 + row16) * 256 + kg * 8;

    bf16x8 wA[8], wB[8];

    for (int i = 0; i < 48; ++i) {
        // step start: issue tile0 load, then A-operand from LDS
        load8(wA, W1p);
        bf16x8 av[8];
        #pragma unroll
        for (int s = 0; s < 8; ++s) av[s] = *(const bf16x8*)&lA[row16][kg * 8 + s * 32];

        // ---- Phase A: [gh | scores] = h @ [w_hh|w_h]^T, 7 tiles, dbuf'd ----
        #pragma unroll
        for (int u = 0; u < 7; ++u) {
            const int t = u * 8 + w;
            if (u < 6) {               // prefetch next A tile (u=5 may hit pad rows)
                if ((u & 1) == 0) load8(wB, W1p + (u + 1) * 32768);
                else              load8(wA, W1p + (u + 1) * 32768);
            } else {                   // u==6: prefetch first C tile (W2, tile w)
                load8(wB, W2p);
            }
            if (t < 51) {
                f32x4 acc = {0.f, 0.f, 0.f, 0.f};
                if ((u & 1) == 0) mfma8(av, wA, acc);
                else              mfma8(av, wB, acc);
                const int n = t * 16 + row16;
                #pragma unroll
                for (int e = 0; e < 4; ++e) lG[kg * 4 + e][n] = acc[e] + biasA[u];
            }
        }
        __syncthreads();

        // ---- B1: softmax over 48 positions (wave w -> batches 2w, 2w+1) ----
        #pragma unroll
        for (int rep = 0; rep < 2; ++rep) {
            int m = w * 2 + rep;
            float val = -3.0e38f;
            if (lane < 48) {
                val = lG[m][768 + lane];
                bool cb = (lC[m] >> i) & 1ull;
                if (lane == i) val += lXW[m][i];
                else if (cb && lane < i) val += lXW[m][lane];
            }
            float mx = val;
            #pragma unroll
            for (int o = 32; o; o >>= 1) mx = fmaxf(mx, __shfl_xor(mx, o));
            float ex = (lane < 48) ? __expf(val - mx) : 0.f;
            float sm = ex;
            #pragma unroll
            for (int o = 32; o; o >>= 1) sm += __shfl_xor(sm, o);
            if (lane < 48) lT[m][lane] = ex / sm;
        }
        __syncthreads();

        // ---- B2: ctx = sum_{j<=i} a_j * x[b,j,:], 8 dims per thread ----
        {
            float acc[8];
            #pragma unroll
            for (int q = 0; q < 8; ++q) acc[q] = 0.f;
            #pragma unroll 4
            for (int j = 0; j <= i; ++j) {
                float aj = lT[mi][j];
                bf16x8 v = *(const bf16x8*)(xr + j * 256);
                #pragma unroll
                for (int q = 0; q < 8; ++q) acc[q] += aj * bf2f(v[q]);
            }
            bf16x8 o;
            #pragma unroll
            for (int q = 0; q < 8; ++q) o[q] = f2bf(acc[q]);
            *(bf16x8*)&lA[mi][dc8] = o;
        }
        __syncthreads();

        // ---- Phase C: gi = ctx @ w_ih^T, 6 tiles, dbuf'd (starts in wB) ----
        {
            bf16x8 cv[8];
            #pragma unroll
            for (int s = 0; s < 8; ++s) cv[s] = *(const bf16x8*)&lA[row16][kg * 8 + s * 32];
            #pragma unroll
            for (int u = 0; u < 6; ++u) {
                const int t = u * 8 + w;
                if (u < 5) {
                    if ((u & 1) == 0) load8(wA, W2p + (u + 1) * 32768);
                    else              load8(wB, W2p + (u + 1) * 32768);
                }
                f32x4 acc = {0.f, 0.f, 0.f, 0.f};
                if ((u & 1) == 0) mfma8(cv, wB, acc);
                else              mfma8(cv, wA, acc);
                const int n = t * 16 + row16;
                if (t < 32) {
                    #pragma unroll
                    for (int e = 0; e < 4; ++e) lG[kg * 4 + e][n] += acc[e] + biasC[u];
                } else {
                    #pragma unroll
                    for (int e = 0; e < 4; ++e) lN[kg * 4 + e][n - 512] = acc[e] + biasC[u];
                }
            }
        }
        __syncthreads();

        // ---- Phase D: GRU update ----
        {
            bf16x8 packed;
            #pragma unroll
            for (int q = 0; q < 8; ++q) {
                int d = dc8 + q;
                float r = 1.f / (1.f + __expf(-lG[mi][d]));
                float z = 1.f / (1.f + __expf(-lG[mi][256 + d]));
                float narg = lN[mi][d] + r * lG[mi][512 + d];
                float nn = 1.f - 2.f / (__expf(2.f * narg) + 1.f);   // tanh
                float hp = (1.f - z) * nn + z * lH[mi][d];
                lH[mi][d] = hp;
                packed[q] = f2bf(hp);
            }
            *(bf16x8*)&lA[mi][dc8] = packed;
        }
        __syncthreads();
    }

    // epilogue: y = sigmoid((hF + se) . w_out + b_out)
    #pragma unroll
    for (int rep = 0; rep < 2; ++rep) {
        int m = w * 2 + rep;
        int b = b0 + m;
        int d = lane * 4;
        float acc = 0.f;
        #pragma unroll
        for (int q = 0; q < 4; ++q)
            acc += (lH[m][d + q] + se[(size_t)b * 256 + d + q]) * w_out[d + q];
        #pragma unroll
        for (int o = 32; o; o >>= 1) acc += __shfl_xor(acc, o);
        if (lane == 0) out[b] = 1.f / (1.f + __expf(-(acc + b_out[0])));
    }
}

extern "C" void kernel_launch(void* const* d_in, const int* in_sizes, int n_in,
                              void* d_out, int out_size, void* d_ws, size_t ws_size,
                              hipStream_t stream) {
    const float* x1   = (const float*)d_in[0];
    const float* x2   = (const float*)d_in[1];
    const float* s    = (const float*)d_in[2];
    const float* w_e1 = (const float*)d_in[3];
    const float* b_e1 = (const float*)d_in[4];
    const float* w_e2 = (const float*)d_in[5];
    const float* b_e2 = (const float*)d_in[6];
    const float* w_s  = (const float*)d_in[7];
    const float* b_s  = (const float*)d_in[8];
    const float* w_x  = (const float*)d_in[9];
    const float* w_h  = (const float*)d_in[10];
    const float* b_h  = (const float*)d_in[11];
    const float* w_ih = (const float*)d_in[12];
    const float* w_hh = (const float*)d_in[13];
    const float* b_ih = (const float*)d_in[14];
    const float* b_hh = (const float*)d_in[15];
    const float* w_out = (const float*)d_in[16];
    const float* b_out = (const float*)d_in[17];
    float* out = (float*)d_out;

    char* ws = (char*)d_ws;
    size_t off = 0;
    auto alloc = [&](size_t bytes) -> void* {
        void* p = ws + off;
        off = (off + bytes + 255) & ~(size_t)255;
        return p;
    };
    short* xb = (short*)alloc((size_t)B_ * L_ * D_ * 2);
    short* W1 = (short*)alloc(896 * 256 * 2);   // 816 rows used; pad to 896 for safe prefetch
    short* W2 = (short*)alloc(768 * 256 * 2);
    float* c0 = (float*)alloc((size_t)B_ * L_ * 4);
    float* xw = (float*)alloc((size_t)B_ * L_ * 4);
    unsigned long long* cb = (unsigned long long*)alloc(B_ * 8);
    float* se = (float*)alloc((size_t)B_ * D_ * 4);

    hipLaunchKernelGGL(k_prep, dim3((816 * 256 + 768 * 256) / 256), dim3(256), 0, stream,
                       w_hh, w_h, w_ih, W1, W2);
    hipLaunchKernelGGL(k_embed, dim3(384), dim3(512), 0, stream,
                       x1, x2, w_e1, b_e1, w_e2, b_e2, xb);
    hipLaunchKernelGGL(k_aux, dim3(6144), dim3(256), 0, stream,
                       x2, w_e2, b_e2, xb, w_x, c0, xw);
    hipLaunchKernelGGL(k_aux2, dim3(512), dim3(256), 0, stream,
                       c0, s, w_s, b_s, cb, se);
    hipLaunchKernelGGL(k_scan, dim3(32), dim3(512), 0, stream,
                       W1, W2, b_hh, b_h, b_ih, xb, xw, cb, se, w_out, b_out, out);
}